// Round 3
// baseline (42.570 us; speedup 1.0000x reference)
//
#include <hip/hip_runtime.h>
#include <math.h>

// BBoxEstimatorLoss: fused per-sample loss + deterministic 2-stage reduction.
// R2: pure-streaming variant. NO dependent gathers — full hrn/hres/srn/sres
// rows loaded as float4 streams, elements selected in registers (VALU idle).
// All loads issued upfront for max memory-level parallelism.
// 4096 blocks x 128 threads x 1 sample/thread = 524288.

constexpr int BS_N = 524288;
constexpr int NBLK = 4096;

__constant__ float G_MEAN[8][3] = {
    {3.88f, 1.63f, 1.53f}, {0.84f, 0.66f, 1.76f}, {1.76f, 0.60f, 1.74f},
    {16.17f, 2.58f, 3.23f}, {3.90f, 1.60f, 1.56f}, {1.73f, 0.58f, 1.37f},
    {0.91f, 0.48f, 1.78f}, {2.06f, 1.86f, 1.66f}
};
__constant__ float G_RCP[8][3] = {
    {1.0f/3.88f, 1.0f/1.63f, 1.0f/1.53f}, {1.0f/0.84f, 1.0f/0.66f, 1.0f/1.76f},
    {1.0f/1.76f, 1.0f/0.60f, 1.0f/1.74f}, {1.0f/16.17f, 1.0f/2.58f, 1.0f/3.23f},
    {1.0f/3.90f, 1.0f/1.60f, 1.0f/1.56f}, {1.0f/1.73f, 1.0f/0.58f, 1.0f/1.37f},
    {1.0f/0.91f, 1.0f/0.48f, 1.0f/1.78f}, {1.0f/2.06f, 1.0f/1.86f, 1.0f/1.66f}
};

__device__ __forceinline__ float huber_pos(float a, float delta) {
    return (a <= delta) ? 0.5f * a * a : delta * (a - 0.5f * delta);
}
__device__ __forceinline__ float huber_norm2(float d2, float delta) {
    return (d2 <= delta * delta) ? 0.5f * d2
                                 : delta * (sqrtf(d2) - 0.5f * delta);
}
__device__ __forceinline__ float sel4(float4 v, int k) {
    float r = v.x;
    r = (k == 1) ? v.y : r;
    r = (k == 2) ? v.z : r;
    r = (k == 3) ? v.w : r;
    return r;
}
__device__ __forceinline__ float sel12(float4 a, float4 b, float4 c, int k) {
    float r = sel4(a, k);
    r = (k >= 4) ? sel4(b, k - 4) : r;
    r = (k >= 8) ? sel4(c, k - 8) : r;
    return r;
}
__device__ __forceinline__ float sel8(float4 a, float4 b, int k) {
    float r = sel4(a, k);
    r = (k >= 4) ? sel4(b, k - 4) : r;
    return r;
}
// select elements [3s, 3s+1, 3s+2] from a 24-float row held in 6 float4s.
// All indices compile-time after unroll -> pure cndmask chain, no scratch.
__device__ __forceinline__ void sel_row3(
    float4 a, float4 b, float4 c, float4 d, float4 e, float4 f, int s,
    float &o0, float &o1, float &o2)
{
    const float r[24] = {a.x,a.y,a.z,a.w, b.x,b.y,b.z,b.w, c.x,c.y,c.z,c.w,
                         d.x,d.y,d.z,d.w, e.x,e.y,e.z,e.w, f.x,f.y,f.z,f.w};
    o0 = r[0]; o1 = r[1]; o2 = r[2];
    #pragma unroll
    for (int k = 1; k < 8; ++k) {
        const bool m = (s == k);
        o0 = m ? r[3*k+0] : o0;
        o1 = m ? r[3*k+1] : o1;
        o2 = m ? r[3*k+2] : o2;
    }
}

__global__ __launch_bounds__(128) void bbox_partial(
    const float* __restrict__ center,
    const float* __restrict__ center_label,
    const float* __restrict__ stage1_center,
    const float* __restrict__ heading_scores,
    const float* __restrict__ hrn,
    const float* __restrict__ hres,
    const int*   __restrict__ hcls_in,
    const float* __restrict__ hres_label,
    const float* __restrict__ size_scores,
    const float* __restrict__ srn,
    const float* __restrict__ sres,
    const int*   __restrict__ scls_in,
    const float* __restrict__ sres_label,
    float* __restrict__ block_out)
{
    const int i = blockIdx.x * 128 + threadIdx.x;

    // ===== issue ALL loads upfront (no load depends on another load) =====
    const int h = hcls_in[i];
    const int s = scls_in[i];

    const float cx = center[3*i+0], cy = center[3*i+1], cz = center[3*i+2];
    const float lx = center_label[3*i+0], ly = center_label[3*i+1], lz = center_label[3*i+2];
    const float tx = stage1_center[3*i+0], ty = stage1_center[3*i+1], tz = stage1_center[3*i+2];
    const float sl0 = sres_label[3*i+0], sl1 = sres_label[3*i+1], sl2 = sres_label[3*i+2];
    const float hrl = hres_label[i];

    const float4* hsp = reinterpret_cast<const float4*>(heading_scores + 12*i);
    const float4 hsA = hsp[0], hsB = hsp[1], hsC = hsp[2];
    const float4* ssp = reinterpret_cast<const float4*>(size_scores + 8*i);
    const float4 ssA = ssp[0], ssB = ssp[1];

    const float4* hnp = reinterpret_cast<const float4*>(hrn + 12*i);
    const float4 hn0 = hnp[0], hn1 = hnp[1], hn2 = hnp[2];
    const float4* hep = reinterpret_cast<const float4*>(hres + 12*i);
    const float4 he0 = hep[0], he1 = hep[1], he2 = hep[2];

    const float4* snp = reinterpret_cast<const float4*>(srn + 24*i);
    const float4 sn0 = snp[0], sn1 = snp[1], sn2 = snp[2],
                 sn3 = snp[3], sn4 = snp[4], sn5 = snp[5];
    const float4* srp = reinterpret_cast<const float4*>(sres + 24*i);
    const float4 sr0 = srp[0], sr1 = srp[1], sr2 = srp[2],
                 sr3 = srp[3], sr4 = srp[4], sr5 = srp[5];

    // ===== compute =====
    float contrib = 0.0f;

    const float dx0 = cx - lx, dy0 = cy - ly, dz0 = cz - lz;
    contrib += huber_norm2(dx0*dx0 + dy0*dy0 + dz0*dz0, 2.0f);      // center_loss
    {
        const float ax = cx - tx, ay = cy - ty, az = cz - tz;
        contrib += huber_norm2(ax*ax + ay*ay + az*az, 1.0f);        // stage1_center_loss
    }

    // heading log-softmax (12)
    {
        float m = fmaxf(fmaxf(fmaxf(hsA.x,hsA.y),fmaxf(hsA.z,hsA.w)),
                  fmaxf(fmaxf(fmaxf(hsB.x,hsB.y),fmaxf(hsB.z,hsB.w)),
                        fmaxf(fmaxf(hsC.x,hsC.y),fmaxf(hsC.z,hsC.w))));
        float se = __expf(hsA.x-m)+__expf(hsA.y-m)+__expf(hsA.z-m)+__expf(hsA.w-m)
                 + __expf(hsB.x-m)+__expf(hsB.y-m)+__expf(hsB.z-m)+__expf(hsB.w-m)
                 + __expf(hsC.x-m)+__expf(hsC.y-m)+__expf(hsC.z-m)+__expf(hsC.w-m);
        contrib += m + __logf(se) - sel12(hsA, hsB, hsC, h);        // heading_class_loss
    }
    // size log-softmax (8)
    {
        float m = fmaxf(fmaxf(fmaxf(ssA.x,ssA.y),fmaxf(ssA.z,ssA.w)),
                        fmaxf(fmaxf(ssB.x,ssB.y),fmaxf(ssB.z,ssB.w)));
        float se = __expf(ssA.x-m)+__expf(ssA.y-m)+__expf(ssA.z-m)+__expf(ssA.w-m)
                 + __expf(ssB.x-m)+__expf(ssB.y-m)+__expf(ssB.z-m)+__expf(ssB.w-m);
        contrib += m + __logf(se) - sel8(ssA, ssB, s);              // size_class_loss
    }

    // register selects replacing gathers
    const float hrnv = sel12(hn0, hn1, hn2, h);
    const float hrev = sel12(he0, he1, he2, h);
    float snv0, snv1, snv2, srv0, srv1, srv2;
    sel_row3(sn0, sn1, sn2, sn3, sn4, sn5, s, snv0, snv1, snv2);
    sel_row3(sr0, sr1, sr2, sr3, sr4, sr5, s, srv0, srv1, srv2);

    // heading residual loss (x20)
    contrib += 20.0f * huber_pos(fabsf(hrnv - hrl * (float)(12.0 / M_PI)), 1.0f);

    // size residual loss (x20)
    const float m0 = G_MEAN[s][0], m1 = G_MEAN[s][1], m2c = G_MEAN[s][2];
    {
        const float e0 = sl0 * G_RCP[s][0] - snv0;
        const float e1 = sl1 * G_RCP[s][1] - snv1;
        const float e2 = sl2 * G_RCP[s][2] - snv2;
        contrib += 20.0f * huber_norm2(e0*e0 + e1*e1 + e2*e2, 1.0f);
    }

    // corner loss (x10, mean over 8 corners)
    {
        const float binc = (float)h * (float)(M_PI / 6.0);
        const float hp = hrev + binc;                 // heading_pred
        const float hg = hrl + binc;                  // heading_label
        const float lp2 = 0.5f * (m0 + srv0);
        const float wp2 = 0.5f * (m1 + srv1);
        const float hp2 = 0.5f * (m2c + srv2);
        const float lg2 = 0.5f * (m0 + sl0);
        const float wg2 = 0.5f * (m1 + sl1);
        const float hg2 = 0.5f * (m2c + sl2);
        float cp, sp, cg, sg;
        __sincosf(hp, &sp, &cp);
        __sincosf(hg, &sg, &cg);
        const float dyh = hp2 - hg2;

        constexpr float SX[8] = {1,1,-1,-1,1,1,-1,-1};
        constexpr float SY[8] = {1,1,1,1,-1,-1,-1,-1};
        constexpr float SZ[8] = {1,-1,-1,1,1,-1,-1,1};
        float csum = 0.0f;
        #pragma unroll
        for (int j = 0; j < 8; ++j) {
            const float axp = SX[j]*lp2, azp = SZ[j]*wp2;
            const float xrp = cp*axp + sp*azp;
            const float zrp = cp*azp - sp*axp;
            const float axg = SX[j]*lg2, azg = SZ[j]*wg2;
            const float xrg = cg*axg + sg*azg;
            const float zrg = cg*azg - sg*axg;
            const float ddy = dy0 + SY[j]*dyh;
            const float u = dx0 + xrp, v = dz0 + zrp;
            const float du1 = u - xrg, dv1 = v - zrg;   // vs gt
            const float du2 = u + xrg, dv2 = v + zrg;   // vs gt_flip (heading+pi)
            const float y2 = ddy*ddy;
            const float dgt = du1*du1 + y2 + dv1*dv1;
            const float dfl = du2*du2 + y2 + dv2*dv2;
            const float mm = fminf(dgt, dfl);
            csum += (mm <= 1.0f) ? 0.5f*mm : sqrtf(mm) - 0.5f;
        }
        contrib += 1.25f * csum;   // 10.0 * (1/8)
    }

    // ===== deterministic block reduction (2 waves) =====
    #pragma unroll
    for (int off = 32; off > 0; off >>= 1)
        contrib += __shfl_down(contrib, off, 64);

    __shared__ float sdata[2];
    const int lane = threadIdx.x & 63;
    const int wid  = threadIdx.x >> 6;
    if (lane == 0) sdata[wid] = contrib;
    __syncthreads();
    if (threadIdx.x == 0)
        block_out[blockIdx.x] = sdata[0] + sdata[1];
}

__global__ __launch_bounds__(256) void bbox_final(
    const float* __restrict__ block_in, float* __restrict__ out)
{
    float ssum = 0.0f;
    for (int i = threadIdx.x; i < NBLK; i += 256)
        ssum += block_in[i];
    #pragma unroll
    for (int off = 32; off > 0; off >>= 1)
        ssum += __shfl_down(ssum, off, 64);

    __shared__ float sdata[4];
    const int lane = threadIdx.x & 63;
    const int wid  = threadIdx.x >> 6;
    if (lane == 0) sdata[wid] = ssum;
    __syncthreads();
    if (threadIdx.x == 0)
        out[0] = ((sdata[0] + sdata[1]) + (sdata[2] + sdata[3])) * (1.0f / (float)BS_N);
}

extern "C" void kernel_launch(void* const* d_in, const int* in_sizes, int n_in,
                              void* d_out, int out_size, void* d_ws, size_t ws_size,
                              hipStream_t stream) {
    const float* center        = (const float*)d_in[0];
    const float* center_label  = (const float*)d_in[1];
    const float* stage1_center = (const float*)d_in[2];
    const float* heading_sc    = (const float*)d_in[3];
    const float* hrn           = (const float*)d_in[4];
    const float* hres          = (const float*)d_in[5];
    const int*   hcls          = (const int*)d_in[6];
    const float* hres_label    = (const float*)d_in[7];
    const float* size_sc       = (const float*)d_in[8];
    const float* srn           = (const float*)d_in[9];
    const float* sres          = (const float*)d_in[10];
    const int*   scls          = (const int*)d_in[11];
    const float* sres_label    = (const float*)d_in[12];

    float* ws  = (float*)d_ws;     // NBLK partial sums (16 KiB)
    float* out = (float*)d_out;

    bbox_partial<<<NBLK, 128, 0, stream>>>(
        center, center_label, stage1_center, heading_sc, hrn, hres,
        hcls, hres_label, size_sc, srn, sres, scls, sres_label, ws);
    bbox_final<<<1, 256, 0, stream>>>(ws, out);
}